// Round 1
// baseline (238.885 us; speedup 1.0000x reference)
//
#include <hip/hip_runtime.h>

#define DIM 128
#define CHUNKS (DIM / 4)   // 32 float4 chunks per row

// edge_attr[e][:] = x[src[e]][:] - x[dst[e]][:]
// one thread per float4 chunk: 32 threads per edge
__global__ void edge_diff_kernel(const float* __restrict__ x,
                                 const int* __restrict__ ei,
                                 float* __restrict__ out,
                                 int E) {
    long long idx = (long long)blockIdx.x * blockDim.x + threadIdx.x;
    int e = (int)(idx >> 5);
    if (e >= E) return;
    int c = ((int)idx & 31) << 2;  // element offset within row

    int s = ei[e];
    int d = ei[E + e];

    const float4 vs = *reinterpret_cast<const float4*>(x + (size_t)s * DIM + c);
    const float4 vd = *reinterpret_cast<const float4*>(x + (size_t)d * DIM + c);
    float4 r;
    r.x = vs.x - vd.x;
    r.y = vs.y - vd.y;
    r.z = vs.z - vd.z;
    r.w = vs.w - vd.w;
    *reinterpret_cast<float4*>(out + (size_t)e * DIM + c) = r;
}

// pairwise cosines of the 3 difference vectors of each hyperedge triple
// 32 lanes per hyperedge; each lane owns a float4 slice of D=128
__global__ void hyper_cos_kernel(const float* __restrict__ x,
                                 const int* __restrict__ hi,
                                 float* __restrict__ out,
                                 int H) {
    long long gid = (long long)blockIdx.x * blockDim.x + threadIdx.x;
    int h = (int)(gid >> 5);
    if (h >= H) return;
    int lane = threadIdx.x & 31;
    int c = lane << 2;

    int ia = hi[h];
    int ib = hi[H + h];
    int ic = hi[2 * H + h];

    float4 ua = *reinterpret_cast<const float4*>(x + (size_t)ia * DIM + c);
    float4 ub = *reinterpret_cast<const float4*>(x + (size_t)ib * DIM + c);
    float4 uc = *reinterpret_cast<const float4*>(x + (size_t)ic * DIM + c);

    const float* pa = reinterpret_cast<const float*>(&ua);
    const float* pb = reinterpret_cast<const float*>(&ub);
    const float* pc = reinterpret_cast<const float*>(&uc);

    float s11 = 0.f, s22 = 0.f, s33 = 0.f;  // |v01|^2, |v02|^2, |v12|^2
    float s12 = 0.f, s13 = 0.f, s23 = 0.f;  // v01.v02, v01.v12, v12.v02
#pragma unroll
    for (int k = 0; k < 4; ++k) {
        float v01 = pa[k] - pb[k];
        float v02 = pa[k] - pc[k];
        float v12 = pb[k] - pc[k];
        s11 = fmaf(v01, v01, s11);
        s22 = fmaf(v02, v02, s22);
        s33 = fmaf(v12, v12, s33);
        s12 = fmaf(v01, v02, s12);
        s13 = fmaf(v01, v12, s13);
        s23 = fmaf(v12, v02, s23);
    }

    // reduce across the 32-lane subgroup (masks < 32 stay within the half-wave)
#pragma unroll
    for (int m = 1; m < 32; m <<= 1) {
        s11 += __shfl_xor(s11, m);
        s22 += __shfl_xor(s22, m);
        s33 += __shfl_xor(s33, m);
        s12 += __shfl_xor(s12, m);
        s13 += __shfl_xor(s13, m);
        s23 += __shfl_xor(s23, m);
    }

    if (lane == 0) {
        float n01 = sqrtf(s11);
        float n02 = sqrtf(s22);
        float n12 = sqrtf(s33);
        float cos1 = s12 / (n01 * n02);
        float cos2 = -s13 / (n01 * n12);
        float cos3 = s23 / (n12 * n02);
        out[(size_t)h * 3 + 0] = cos1;
        out[(size_t)h * 3 + 1] = cos2;
        out[(size_t)h * 3 + 2] = cos3;
    }
}

extern "C" void kernel_launch(void* const* d_in, const int* in_sizes, int n_in,
                              void* d_out, int out_size, void* d_ws, size_t ws_size,
                              hipStream_t stream) {
    const float* x  = (const float*)d_in[0];
    const int*   ei = (const int*)d_in[1];   // (2, E)
    const int*   hi = (const int*)d_in[2];   // (3, H)

    const int E = in_sizes[1] / 2;
    const int H = in_sizes[2] / 3;

    float* out_edge  = (float*)d_out;                       // (E, D)
    float* out_hyper = out_edge + (size_t)E * DIM;          // (H, 3)

    {
        long long total = (long long)E * CHUNKS;            // threads
        int block = 256;
        long long grid = (total + block - 1) / block;
        edge_diff_kernel<<<(dim3)(unsigned)grid, block, 0, stream>>>(x, ei, out_edge, E);
    }
    {
        long long total = (long long)H * 32;                // threads
        int block = 256;
        long long grid = (total + block - 1) / block;
        hyper_cos_kernel<<<(dim3)(unsigned)grid, block, 0, stream>>>(x, hi, out_hyper, H);
    }
}

// Round 3
// 228.153 us; speedup vs baseline: 1.0470x; 1.0470x over previous
//
#include <hip/hip_runtime.h>

#define DIM 128

typedef float v4f __attribute__((ext_vector_type(4)));

// Fused kernel: blocks are proportionally interleaved between two roles via a
// Bresenham mapping so edge-diff (write-heavy) and hyper-cosine (read-heavy)
// work is co-resident on the machine and their bandwidth demands overlap.
//
// Edge role:  16 threads/edge, each thread owns float4 chunks {sub, sub+16}
//             (unit-stride across the 16-lane group per instruction).
// Hyper role: 16 threads/hyperedge, same chunk ownership; 3 accumulators
//             (s11=|v01|^2, s22=|v02|^2, s12=v01.v02); v12 = v02 - v01 gives
//             s33 = s11+s22-2*s12, v01.v12 = s12-s11, v12.v02 = s22-s12.
__global__ __launch_bounds__(256) void fused_kernel(
    const float* __restrict__ x,
    const int* __restrict__ ei,
    const int* __restrict__ hi,
    float* __restrict__ out_edge,
    float* __restrict__ out_hyper,
    int E, int H, int nEB, int T) {

    long long b = blockIdx.x;
    long long aBefore = (b * (long long)nEB) / T;
    long long aAfter  = ((b + 1) * (long long)nEB) / T;

    int t   = threadIdx.x;
    int grp = t >> 4;    // 16 units per block
    int sub = t & 15;    // 16 lanes per unit
    int c0  = sub * 4;   // float offset of first float4 chunk
    int c1  = c0 + 64;   // second chunk (chunks sub and sub+16)

    if (aAfter > aBefore) {
        // ---------------- edge block ----------------
        long long e = aBefore * 16 + grp;
        if (e >= E) return;
        int s = ei[e];
        int d = ei[(size_t)E + e];
        const float* xs = x + (size_t)s * DIM;
        const float* xd = x + (size_t)d * DIM;
        v4f s0 = *reinterpret_cast<const v4f*>(xs + c0);
        v4f s1 = *reinterpret_cast<const v4f*>(xs + c1);
        v4f d0 = *reinterpret_cast<const v4f*>(xd + c0);
        v4f d1 = *reinterpret_cast<const v4f*>(xd + c1);
        v4f r0 = s0 - d0;
        v4f r1 = s1 - d1;
        float* po = out_edge + (size_t)e * DIM;
        __builtin_nontemporal_store(r0, reinterpret_cast<v4f*>(po + c0));
        __builtin_nontemporal_store(r1, reinterpret_cast<v4f*>(po + c1));
    } else {
        // ---------------- hyper block ----------------
        long long hb = b - aBefore;
        long long h  = hb * 16 + grp;
        if (h >= H) return;
        int ia = hi[h];
        int ib = hi[(size_t)H + h];
        int ic = hi[2 * (size_t)H + h];
        const float* pa = x + (size_t)ia * DIM;
        const float* pb = x + (size_t)ib * DIM;
        const float* pc = x + (size_t)ic * DIM;

        v4f a0 = *reinterpret_cast<const v4f*>(pa + c0);
        v4f a1 = *reinterpret_cast<const v4f*>(pa + c1);
        v4f b0 = *reinterpret_cast<const v4f*>(pb + c0);
        v4f b1 = *reinterpret_cast<const v4f*>(pb + c1);
        v4f q0 = *reinterpret_cast<const v4f*>(pc + c0);
        v4f q1 = *reinterpret_cast<const v4f*>(pc + c1);

        float s11 = 0.f, s22 = 0.f, s12 = 0.f;
#define ACC(A, B, C) { float v01 = (A) - (B); float v02 = (A) - (C); \
        s11 = fmaf(v01, v01, s11); s22 = fmaf(v02, v02, s22); s12 = fmaf(v01, v02, s12); }
        ACC(a0.x, b0.x, q0.x) ACC(a0.y, b0.y, q0.y) ACC(a0.z, b0.z, q0.z) ACC(a0.w, b0.w, q0.w)
        ACC(a1.x, b1.x, q1.x) ACC(a1.y, b1.y, q1.y) ACC(a1.z, b1.z, q1.z) ACC(a1.w, b1.w, q1.w)
#undef ACC

        // reduce across the 16-lane unit (xor masks < 16 stay in the unit)
#pragma unroll
        for (int m = 1; m < 16; m <<= 1) {
            s11 += __shfl_xor(s11, m);
            s22 += __shfl_xor(s22, m);
            s12 += __shfl_xor(s12, m);
        }

        if (sub == 0) {
            float s33 = s11 + s22 - 2.f * s12;   // |v12|^2, v12 = v02 - v01
            float n01 = sqrtf(s11);
            float n02 = sqrtf(s22);
            float n12 = sqrtf(s33);
            float cos1 = s12 / (n01 * n02);
            float cos2 = (s11 - s12) / (n01 * n12);   // -(v01.v12)/(n01*n12)
            float cos3 = (s22 - s12) / (n12 * n02);   // (v12.v02)/(n12*n02)
            float* po = out_hyper + (size_t)h * 3;
            po[0] = cos1;
            po[1] = cos2;
            po[2] = cos3;
        }
    }
}

extern "C" void kernel_launch(void* const* d_in, const int* in_sizes, int n_in,
                              void* d_out, int out_size, void* d_ws, size_t ws_size,
                              hipStream_t stream) {
    const float* x  = (const float*)d_in[0];
    const int*   ei = (const int*)d_in[1];   // (2, E)
    const int*   hi = (const int*)d_in[2];   // (3, H)

    const int E = in_sizes[1] / 2;
    const int H = in_sizes[2] / 3;

    float* out_edge  = (float*)d_out;                  // (E, D)
    float* out_hyper = out_edge + (size_t)E * DIM;     // (H, 3)

    int nEB = (E + 15) / 16;   // 16 edges per block
    int nHB = (H + 15) / 16;   // 16 hyperedges per block
    int T   = nEB + nHB;

    fused_kernel<<<T, 256, 0, stream>>>(x, ei, hi, out_edge, out_hyper, E, H, nEB, T);
}

// Round 4
// 161.244 us; speedup vs baseline: 1.4815x; 1.4150x over previous
//
#include <hip/hip_runtime.h>

#define DIM 128

typedef float    v4f __attribute__((ext_vector_type(4)));
typedef _Float16 h8  __attribute__((ext_vector_type(8)));

// ---------- prep: x (f32) -> xh (f16) in workspace ----------
__global__ __launch_bounds__(256) void cvt_kernel(const float* __restrict__ x,
                                                  _Float16* __restrict__ xh,
                                                  long long total8) {
    long long i = (long long)blockIdx.x * blockDim.x + threadIdx.x;
    if (i >= total8) return;
    v4f f0 = *reinterpret_cast<const v4f*>(x + i * 8);
    v4f f1 = *reinterpret_cast<const v4f*>(x + i * 8 + 4);
    h8 o;
    o[0] = (_Float16)f0.x; o[1] = (_Float16)f0.y;
    o[2] = (_Float16)f0.z; o[3] = (_Float16)f0.w;
    o[4] = (_Float16)f1.x; o[5] = (_Float16)f1.y;
    o[6] = (_Float16)f1.z; o[7] = (_Float16)f1.w;
    *reinterpret_cast<h8*>(xh + i * 8) = o;
}

// ---------- fused main kernel (fp16 gathers) ----------
// Edge role:  16 lanes/edge, each lane owns 8 consecutive features (one 16-B
//             fp16 load per row), computes diff in f32, nt-stores 2 float4.
// Hyper role: 16 lanes/hyperedge, 3 fp16 row loads, 3 accumulators
//             (s11=|v01|^2, s22=|v02|^2, s12=v01.v02); s33 = s11+s22-2*s12.
__global__ __launch_bounds__(256) void fused_f16_kernel(
    const _Float16* __restrict__ xh,
    const int* __restrict__ ei,
    const int* __restrict__ hi,
    float* __restrict__ out_edge,
    float* __restrict__ out_hyper,
    int E, int H, int nEB, int T) {

    long long b = blockIdx.x;
    long long aBefore = (b * (long long)nEB) / T;
    long long aAfter  = ((b + 1) * (long long)nEB) / T;

    int t   = threadIdx.x;
    int grp = t >> 4;    // 16 units per block
    int sub = t & 15;    // 16 lanes per unit
    int c   = sub * 8;   // feature offset (8 features per lane)

    if (aAfter > aBefore) {
        // ---------------- edge block ----------------
        long long e = aBefore * 16 + grp;
        if (e >= E) return;
        int s = ei[e];
        int d = ei[(size_t)E + e];
        h8 hs = *reinterpret_cast<const h8*>(xh + (size_t)s * DIM + c);
        h8 hd = *reinterpret_cast<const h8*>(xh + (size_t)d * DIM + c);
        v4f r0, r1;
        r0.x = (float)hs[0] - (float)hd[0];
        r0.y = (float)hs[1] - (float)hd[1];
        r0.z = (float)hs[2] - (float)hd[2];
        r0.w = (float)hs[3] - (float)hd[3];
        r1.x = (float)hs[4] - (float)hd[4];
        r1.y = (float)hs[5] - (float)hd[5];
        r1.z = (float)hs[6] - (float)hd[6];
        r1.w = (float)hs[7] - (float)hd[7];
        float* po = out_edge + (size_t)e * DIM + c;
        __builtin_nontemporal_store(r0, reinterpret_cast<v4f*>(po));
        __builtin_nontemporal_store(r1, reinterpret_cast<v4f*>(po + 4));
    } else {
        // ---------------- hyper block ----------------
        long long hb = b - aBefore;
        long long h  = hb * 16 + grp;
        if (h >= H) return;
        int ia = hi[h];
        int ib = hi[(size_t)H + h];
        int ic = hi[2 * (size_t)H + h];
        h8 ha = *reinterpret_cast<const h8*>(xh + (size_t)ia * DIM + c);
        h8 hb8 = *reinterpret_cast<const h8*>(xh + (size_t)ib * DIM + c);
        h8 hc = *reinterpret_cast<const h8*>(xh + (size_t)ic * DIM + c);

        float s11 = 0.f, s22 = 0.f, s12 = 0.f;
#pragma unroll
        for (int k = 0; k < 8; ++k) {
            float v01 = (float)ha[k] - (float)hb8[k];
            float v02 = (float)ha[k] - (float)hc[k];
            s11 = fmaf(v01, v01, s11);
            s22 = fmaf(v02, v02, s22);
            s12 = fmaf(v01, v02, s12);
        }

#pragma unroll
        for (int m = 1; m < 16; m <<= 1) {
            s11 += __shfl_xor(s11, m);
            s22 += __shfl_xor(s22, m);
            s12 += __shfl_xor(s12, m);
        }

        if (sub == 0) {
            float s33 = s11 + s22 - 2.f * s12;   // |v12|^2, v12 = v02 - v01
            float n01 = sqrtf(s11);
            float n02 = sqrtf(s22);
            float n12 = sqrtf(s33);
            float* po = out_hyper + (size_t)h * 3;
            po[0] = s12 / (n01 * n02);
            po[1] = (s11 - s12) / (n01 * n12);
            po[2] = (s22 - s12) / (n12 * n02);
        }
    }
}

// ---------- fallback: f32 gathers straight from x (if ws too small) ----------
__global__ __launch_bounds__(256) void fused_f32_kernel(
    const float* __restrict__ x,
    const int* __restrict__ ei,
    const int* __restrict__ hi,
    float* __restrict__ out_edge,
    float* __restrict__ out_hyper,
    int E, int H, int nEB, int T) {

    long long b = blockIdx.x;
    long long aBefore = (b * (long long)nEB) / T;
    long long aAfter  = ((b + 1) * (long long)nEB) / T;

    int t   = threadIdx.x;
    int grp = t >> 4;
    int sub = t & 15;
    int c0  = sub * 4;
    int c1  = c0 + 64;

    if (aAfter > aBefore) {
        long long e = aBefore * 16 + grp;
        if (e >= E) return;
        int s = ei[e];
        int d = ei[(size_t)E + e];
        const float* xs = x + (size_t)s * DIM;
        const float* xd = x + (size_t)d * DIM;
        v4f s0 = *reinterpret_cast<const v4f*>(xs + c0);
        v4f s1 = *reinterpret_cast<const v4f*>(xs + c1);
        v4f d0 = *reinterpret_cast<const v4f*>(xd + c0);
        v4f d1 = *reinterpret_cast<const v4f*>(xd + c1);
        v4f r0 = s0 - d0;
        v4f r1 = s1 - d1;
        float* po = out_edge + (size_t)e * DIM;
        __builtin_nontemporal_store(r0, reinterpret_cast<v4f*>(po + c0));
        __builtin_nontemporal_store(r1, reinterpret_cast<v4f*>(po + c1));
    } else {
        long long hb = b - aBefore;
        long long h  = hb * 16 + grp;
        if (h >= H) return;
        int ia = hi[h];
        int ib = hi[(size_t)H + h];
        int ic = hi[2 * (size_t)H + h];
        const float* pa = x + (size_t)ia * DIM;
        const float* pb = x + (size_t)ib * DIM;
        const float* pc = x + (size_t)ic * DIM;
        v4f a0 = *reinterpret_cast<const v4f*>(pa + c0);
        v4f a1 = *reinterpret_cast<const v4f*>(pa + c1);
        v4f b0 = *reinterpret_cast<const v4f*>(pb + c0);
        v4f b1 = *reinterpret_cast<const v4f*>(pb + c1);
        v4f q0 = *reinterpret_cast<const v4f*>(pc + c0);
        v4f q1 = *reinterpret_cast<const v4f*>(pc + c1);

        float s11 = 0.f, s22 = 0.f, s12 = 0.f;
#define ACC(A, B, C) { float v01 = (A) - (B); float v02 = (A) - (C); \
        s11 = fmaf(v01, v01, s11); s22 = fmaf(v02, v02, s22); s12 = fmaf(v01, v02, s12); }
        ACC(a0.x, b0.x, q0.x) ACC(a0.y, b0.y, q0.y) ACC(a0.z, b0.z, q0.z) ACC(a0.w, b0.w, q0.w)
        ACC(a1.x, b1.x, q1.x) ACC(a1.y, b1.y, q1.y) ACC(a1.z, b1.z, q1.z) ACC(a1.w, b1.w, q1.w)
#undef ACC
#pragma unroll
        for (int m = 1; m < 16; m <<= 1) {
            s11 += __shfl_xor(s11, m);
            s22 += __shfl_xor(s22, m);
            s12 += __shfl_xor(s12, m);
        }
        if (sub == 0) {
            float s33 = s11 + s22 - 2.f * s12;
            float n01 = sqrtf(s11);
            float n02 = sqrtf(s22);
            float n12 = sqrtf(s33);
            float* po = out_hyper + (size_t)h * 3;
            po[0] = s12 / (n01 * n02);
            po[1] = (s11 - s12) / (n01 * n12);
            po[2] = (s22 - s12) / (n12 * n02);
        }
    }
}

extern "C" void kernel_launch(void* const* d_in, const int* in_sizes, int n_in,
                              void* d_out, int out_size, void* d_ws, size_t ws_size,
                              hipStream_t stream) {
    const float* x  = (const float*)d_in[0];
    const int*   ei = (const int*)d_in[1];   // (2, E)
    const int*   hi = (const int*)d_in[2];   // (3, H)

    const long long ND = (long long)in_sizes[0];   // N * D
    const int E = in_sizes[1] / 2;
    const int H = in_sizes[2] / 3;

    float* out_edge  = (float*)d_out;                  // (E, D)
    float* out_hyper = out_edge + (size_t)E * DIM;     // (H, 3)

    int nEB = (E + 15) / 16;
    int nHB = (H + 15) / 16;
    int T   = nEB + nHB;

    const size_t need = (size_t)ND * sizeof(_Float16);
    if (ws_size >= need) {
        _Float16* xh = (_Float16*)d_ws;
        long long total8 = ND / 8;
        int block = 256;
        long long grid = (total8 + block - 1) / block;
        cvt_kernel<<<(dim3)(unsigned)grid, block, 0, stream>>>(x, xh, total8);
        fused_f16_kernel<<<T, 256, 0, stream>>>(xh, ei, hi, out_edge, out_hyper,
                                                E, H, nEB, T);
    } else {
        fused_f32_kernel<<<T, 256, 0, stream>>>(x, ei, hi, out_edge, out_hyper,
                                                E, H, nEB, T);
    }
}

// Round 5
// 129.848 us; speedup vs baseline: 1.8397x; 1.2418x over previous
//
#include <hip/hip_runtime.h>

#define DIM 128

typedef float    v4f __attribute__((ext_vector_type(4)));
typedef _Float16 h8  __attribute__((ext_vector_type(8)));

// ---------------- prep: x(f32) -> row-major fp16 AND slice-major fp16 ----------------
// Slice-major: 4 slices of 32 features; slice k is a contiguous N*32-element
// block (3.2 MB @ N=50k) so it fits a 4 MiB per-XCD L2.
__global__ __launch_bounds__(256) void cvt2_kernel(const float* __restrict__ x,
                                                   _Float16* __restrict__ xrow,
                                                   _Float16* __restrict__ xsl,
                                                   long long N, long long total8) {
    long long i = (long long)blockIdx.x * blockDim.x + threadIdx.x;
    if (i >= total8) return;
    long long r = i >> 4;      // row
    int o = (int)(i & 15);     // feature octet 0..15
    v4f f0 = *reinterpret_cast<const v4f*>(x + i * 8);
    v4f f1 = *reinterpret_cast<const v4f*>(x + i * 8 + 4);
    h8 v;
    v[0] = (_Float16)f0.x; v[1] = (_Float16)f0.y;
    v[2] = (_Float16)f0.z; v[3] = (_Float16)f0.w;
    v[4] = (_Float16)f1.x; v[5] = (_Float16)f1.y;
    v[6] = (_Float16)f1.z; v[7] = (_Float16)f1.w;
    *reinterpret_cast<h8*>(xrow + i * 8) = v;
    int k = o >> 2;            // slice 0..3
    int q = o & 3;             // octet within slice
    *reinterpret_cast<h8*>(xsl + (size_t)k * N * 32 + r * 32 + q * 8) = v;
}

// ---------------- edge kernel, feature-sharded ----------------
// block b: slice k = b&3, edges [ (b>>2)*64, +64 ).  4 lanes per edge, each
// lane owns 8 features of the 32-feature slice.  With blockIdx round-robin
// over 8 XCDs, XCD x sees only slice x%4 -> slice stays L2-resident.
__global__ __launch_bounds__(256) void edge_sliced_kernel(
    const _Float16* __restrict__ xsl,
    const int* __restrict__ ei,
    float* __restrict__ out_edge,
    int E, long long N) {

    int b = blockIdx.x;
    int k = b & 3;
    long long chunk = (long long)(b >> 2);
    int t = threadIdx.x;
    long long e = chunk * 64 + (t >> 2);
    if (e >= E) return;
    int j = t & 3;             // feature-octet lane within slice

    int s = ei[e];
    int d = ei[(size_t)E + e];
    const _Float16* base = xsl + (size_t)k * N * 32;
    h8 hs = *reinterpret_cast<const h8*>(base + (size_t)s * 32 + j * 8);
    h8 hd = *reinterpret_cast<const h8*>(base + (size_t)d * 32 + j * 8);
    v4f r0, r1;
    r0.x = (float)hs[0] - (float)hd[0];
    r0.y = (float)hs[1] - (float)hd[1];
    r0.z = (float)hs[2] - (float)hd[2];
    r0.w = (float)hs[3] - (float)hd[3];
    r1.x = (float)hs[4] - (float)hd[4];
    r1.y = (float)hs[5] - (float)hd[5];
    r1.z = (float)hs[6] - (float)hd[6];
    r1.w = (float)hs[7] - (float)hd[7];
    float* po = out_edge + (size_t)e * DIM + k * 32 + j * 8;
    __builtin_nontemporal_store(r0, reinterpret_cast<v4f*>(po));
    __builtin_nontemporal_store(r1, reinterpret_cast<v4f*>(po + 4));
}

// ---------------- hyper kernel (fp16 row-major gathers) ----------------
__global__ __launch_bounds__(256) void hyper_f16_kernel(
    const _Float16* __restrict__ xh,
    const int* __restrict__ hi,
    float* __restrict__ out_hyper,
    int H) {

    long long gid = (long long)blockIdx.x * blockDim.x + threadIdx.x;
    long long h = gid >> 4;
    if (h >= H) return;
    int sub = (int)(gid & 15);
    int c = sub * 8;

    int ia = hi[h];
    int ib = hi[(size_t)H + h];
    int ic = hi[2 * (size_t)H + h];
    h8 ha = *reinterpret_cast<const h8*>(xh + (size_t)ia * DIM + c);
    h8 hb = *reinterpret_cast<const h8*>(xh + (size_t)ib * DIM + c);
    h8 hc = *reinterpret_cast<const h8*>(xh + (size_t)ic * DIM + c);

    float s11 = 0.f, s22 = 0.f, s12 = 0.f;
#pragma unroll
    for (int k = 0; k < 8; ++k) {
        float v01 = (float)ha[k] - (float)hb[k];
        float v02 = (float)ha[k] - (float)hc[k];
        s11 = fmaf(v01, v01, s11);
        s22 = fmaf(v02, v02, s22);
        s12 = fmaf(v01, v02, s12);
    }
#pragma unroll
    for (int m = 1; m < 16; m <<= 1) {
        s11 += __shfl_xor(s11, m);
        s22 += __shfl_xor(s22, m);
        s12 += __shfl_xor(s12, m);
    }
    if (sub == 0) {
        float s33 = s11 + s22 - 2.f * s12;   // |v12|^2, v12 = v02 - v01
        float n01 = sqrtf(s11);
        float n02 = sqrtf(s22);
        float n12 = sqrtf(s33);
        float* po = out_hyper + (size_t)h * 3;
        po[0] = s12 / (n01 * n02);
        po[1] = (s11 - s12) / (n01 * n12);
        po[2] = (s22 - s12) / (n12 * n02);
    }
}

// ---------------- fallback: fused f32 straight from x ----------------
__global__ __launch_bounds__(256) void fused_f32_kernel(
    const float* __restrict__ x,
    const int* __restrict__ ei,
    const int* __restrict__ hi,
    float* __restrict__ out_edge,
    float* __restrict__ out_hyper,
    int E, int H, int nEB, int T) {

    long long b = blockIdx.x;
    long long aBefore = (b * (long long)nEB) / T;
    long long aAfter  = ((b + 1) * (long long)nEB) / T;
    int t   = threadIdx.x;
    int grp = t >> 4;
    int sub = t & 15;
    int c0  = sub * 4;
    int c1  = c0 + 64;

    if (aAfter > aBefore) {
        long long e = aBefore * 16 + grp;
        if (e >= E) return;
        int s = ei[e];
        int d = ei[(size_t)E + e];
        const float* xs = x + (size_t)s * DIM;
        const float* xd = x + (size_t)d * DIM;
        v4f s0 = *reinterpret_cast<const v4f*>(xs + c0);
        v4f s1 = *reinterpret_cast<const v4f*>(xs + c1);
        v4f d0 = *reinterpret_cast<const v4f*>(xd + c0);
        v4f d1 = *reinterpret_cast<const v4f*>(xd + c1);
        v4f r0 = s0 - d0;
        v4f r1 = s1 - d1;
        float* po = out_edge + (size_t)e * DIM;
        __builtin_nontemporal_store(r0, reinterpret_cast<v4f*>(po + c0));
        __builtin_nontemporal_store(r1, reinterpret_cast<v4f*>(po + c1));
    } else {
        long long hb = b - aBefore;
        long long h  = hb * 16 + grp;
        if (h >= H) return;
        int ia = hi[h];
        int ib = hi[(size_t)H + h];
        int ic = hi[2 * (size_t)H + h];
        const float* pa = x + (size_t)ia * DIM;
        const float* pb = x + (size_t)ib * DIM;
        const float* pc = x + (size_t)ic * DIM;
        v4f a0 = *reinterpret_cast<const v4f*>(pa + c0);
        v4f a1 = *reinterpret_cast<const v4f*>(pa + c1);
        v4f b0 = *reinterpret_cast<const v4f*>(pb + c0);
        v4f b1 = *reinterpret_cast<const v4f*>(pb + c1);
        v4f q0 = *reinterpret_cast<const v4f*>(pc + c0);
        v4f q1 = *reinterpret_cast<const v4f*>(pc + c1);
        float s11 = 0.f, s22 = 0.f, s12 = 0.f;
#define ACC(A, B, C) { float v01 = (A) - (B); float v02 = (A) - (C); \
        s11 = fmaf(v01, v01, s11); s22 = fmaf(v02, v02, s22); s12 = fmaf(v01, v02, s12); }
        ACC(a0.x, b0.x, q0.x) ACC(a0.y, b0.y, q0.y) ACC(a0.z, b0.z, q0.z) ACC(a0.w, b0.w, q0.w)
        ACC(a1.x, b1.x, q1.x) ACC(a1.y, b1.y, q1.y) ACC(a1.z, b1.z, q1.z) ACC(a1.w, b1.w, q1.w)
#undef ACC
#pragma unroll
        for (int m = 1; m < 16; m <<= 1) {
            s11 += __shfl_xor(s11, m);
            s22 += __shfl_xor(s22, m);
            s12 += __shfl_xor(s12, m);
        }
        if (sub == 0) {
            float s33 = s11 + s22 - 2.f * s12;
            float n01 = sqrtf(s11);
            float n02 = sqrtf(s22);
            float n12 = sqrtf(s33);
            float* po = out_hyper + (size_t)h * 3;
            po[0] = s12 / (n01 * n02);
            po[1] = (s11 - s12) / (n01 * n12);
            po[2] = (s22 - s12) / (n12 * n02);
        }
    }
}

extern "C" void kernel_launch(void* const* d_in, const int* in_sizes, int n_in,
                              void* d_out, int out_size, void* d_ws, size_t ws_size,
                              hipStream_t stream) {
    const float* x  = (const float*)d_in[0];
    const int*   ei = (const int*)d_in[1];   // (2, E)
    const int*   hi = (const int*)d_in[2];   // (3, H)

    const long long ND = (long long)in_sizes[0];   // N * D
    const long long N  = ND / DIM;
    const int E = in_sizes[1] / 2;
    const int H = in_sizes[2] / 3;

    float* out_edge  = (float*)d_out;                  // (E, D)
    float* out_hyper = out_edge + (size_t)E * DIM;     // (H, 3)

    const size_t need = (size_t)ND * 2 * sizeof(_Float16);  // row-major + sliced
    if (ws_size >= need) {
        _Float16* xrow = (_Float16*)d_ws;
        _Float16* xsl  = xrow + ND;
        long long total8 = ND / 8;
        {
            int block = 256;
            long long grid = (total8 + block - 1) / block;
            cvt2_kernel<<<(dim3)(unsigned)grid, block, 0, stream>>>(x, xrow, xsl, N, total8);
        }
        {
            // 64 edges per block per slice, 4 slices
            long long chunks = ((long long)E + 63) / 64;
            long long grid = chunks * 4;
            edge_sliced_kernel<<<(dim3)(unsigned)grid, 256, 0, stream>>>(xsl, ei, out_edge, E, N);
        }
        {
            long long total = (long long)H * 16;
            long long grid = (total + 255) / 256;
            hyper_f16_kernel<<<(dim3)(unsigned)grid, 256, 0, stream>>>(xrow, hi, out_hyper, H);
        }
    } else {
        int nEB = (E + 15) / 16;
        int nHB = (H + 15) / 16;
        int T   = nEB + nHB;
        fused_f32_kernel<<<T, 256, 0, stream>>>(x, ei, hi, out_edge, out_hyper, E, H, nEB, T);
    }
}

// Round 6
// 112.065 us; speedup vs baseline: 2.1317x; 1.1587x over previous
//
#include <hip/hip_runtime.h>

#define DIM 128

typedef float    v4f __attribute__((ext_vector_type(4)));
typedef _Float16 h8  __attribute__((ext_vector_type(8)));

// ---------------- prep: x(f32) -> slice-major fp16 ----------------
// 4 slices of 32 features; slice k is a contiguous N*32-element block
// (3.2 MB @ N=50k) so it fits a 4 MiB per-XCD L2.
__global__ __launch_bounds__(256) void cvt_sliced_kernel(const float* __restrict__ x,
                                                         _Float16* __restrict__ xsl,
                                                         long long N, long long total8) {
    long long i = (long long)blockIdx.x * blockDim.x + threadIdx.x;
    if (i >= total8) return;
    long long r = i >> 4;      // row
    int o = (int)(i & 15);     // feature octet 0..15
    v4f f0 = *reinterpret_cast<const v4f*>(x + i * 8);
    v4f f1 = *reinterpret_cast<const v4f*>(x + i * 8 + 4);
    h8 v;
    v[0] = (_Float16)f0.x; v[1] = (_Float16)f0.y;
    v[2] = (_Float16)f0.z; v[3] = (_Float16)f0.w;
    v[4] = (_Float16)f1.x; v[5] = (_Float16)f1.y;
    v[6] = (_Float16)f1.z; v[7] = (_Float16)f1.w;
    int k = o >> 2;            // slice 0..3
    int q = o & 3;             // octet within slice
    *reinterpret_cast<h8*>(xsl + (size_t)k * N * 32 + r * 32 + q * 8) = v;
}

// ---------------- fused pass A: edge diff + hyper partial sums ----------------
// slice k = blockIdx&3 for BOTH roles (keeps XCD x -> slice x%4 L2 pinning,
// since blockIdx round-robins XCDs). Bresenham over chunk index splits chunks
// proportionally between edge chunks (64 edges) and hyper chunks (64 h-edges).
// Edge unit:  4 lanes x 8 features of the 32-feature slice -> nt-store 2 v4f.
// Hyper unit: 4 lanes x 8 features -> partial s11,s22,s12 over the slice;
//             2-step shfl_xor reduce; lanes 0..2 write one plane each:
//             P[(j*4+k)*H + h], j in {s11,s22,s12}.
__global__ __launch_bounds__(256) void fusedA_kernel(
    const _Float16* __restrict__ xsl,
    const int* __restrict__ ei,
    const int* __restrict__ hi,
    float* __restrict__ out_edge,
    float* __restrict__ P,
    int E, int H, long long N, int CE, int C) {

    int b = blockIdx.x;
    int k = b & 3;
    long long c = (long long)(b >> 2);
    long long eBefore = (c * CE) / C;
    long long eAfter  = ((c + 1) * CE) / C;

    int t   = threadIdx.x;
    int unit = t >> 2;         // 64 units per block
    int sub  = t & 3;          // 4 lanes per unit
    const _Float16* base = xsl + (size_t)k * N * 32;

    if (eAfter > eBefore) {
        // ---------------- edge chunk ----------------
        long long e = eBefore * 64 + unit;
        if (e >= E) return;
        int s = ei[e];
        int d = ei[(size_t)E + e];
        h8 hs = *reinterpret_cast<const h8*>(base + (size_t)s * 32 + sub * 8);
        h8 hd = *reinterpret_cast<const h8*>(base + (size_t)d * 32 + sub * 8);
        v4f r0, r1;
        r0.x = (float)hs[0] - (float)hd[0];
        r0.y = (float)hs[1] - (float)hd[1];
        r0.z = (float)hs[2] - (float)hd[2];
        r0.w = (float)hs[3] - (float)hd[3];
        r1.x = (float)hs[4] - (float)hd[4];
        r1.y = (float)hs[5] - (float)hd[5];
        r1.z = (float)hs[6] - (float)hd[6];
        r1.w = (float)hs[7] - (float)hd[7];
        float* po = out_edge + (size_t)e * DIM + k * 32 + sub * 8;
        __builtin_nontemporal_store(r0, reinterpret_cast<v4f*>(po));
        __builtin_nontemporal_store(r1, reinterpret_cast<v4f*>(po + 4));
    } else {
        // ---------------- hyper chunk ----------------
        long long hc = c - eBefore;
        long long h  = hc * 64 + unit;
        if (h >= H) return;
        int ia = hi[h];
        int ib = hi[(size_t)H + h];
        int ic = hi[2 * (size_t)H + h];
        h8 ha  = *reinterpret_cast<const h8*>(base + (size_t)ia * 32 + sub * 8);
        h8 hb8 = *reinterpret_cast<const h8*>(base + (size_t)ib * 32 + sub * 8);
        h8 hcv = *reinterpret_cast<const h8*>(base + (size_t)ic * 32 + sub * 8);

        float s11 = 0.f, s22 = 0.f, s12 = 0.f;
#pragma unroll
        for (int q = 0; q < 8; ++q) {
            float v01 = (float)ha[q] - (float)hb8[q];
            float v02 = (float)ha[q] - (float)hcv[q];
            s11 = fmaf(v01, v01, s11);
            s22 = fmaf(v02, v02, s22);
            s12 = fmaf(v01, v02, s12);
        }
        // reduce across the 4-lane unit
        s11 += __shfl_xor(s11, 1); s11 += __shfl_xor(s11, 2);
        s22 += __shfl_xor(s22, 1); s22 += __shfl_xor(s22, 2);
        s12 += __shfl_xor(s12, 1); s12 += __shfl_xor(s12, 2);

        if (sub < 3) {
            float v = (sub == 0) ? s11 : (sub == 1) ? s22 : s12;
            P[((size_t)sub * 4 + k) * H + h] = v;
        }
    }
}

// ---------------- pass B: combine slice partials -> cosines ----------------
__global__ __launch_bounds__(256) void hyperB_kernel(
    const float* __restrict__ P,
    float* __restrict__ out_hyper,
    int H) {
    long long h = (long long)blockIdx.x * blockDim.x + threadIdx.x;
    if (h >= H) return;
    float s11 = 0.f, s22 = 0.f, s12 = 0.f;
#pragma unroll
    for (int k = 0; k < 4; ++k) {
        s11 += P[((size_t)0 * 4 + k) * H + h];
        s22 += P[((size_t)1 * 4 + k) * H + h];
        s12 += P[((size_t)2 * 4 + k) * H + h];
    }
    float s33 = s11 + s22 - 2.f * s12;   // |v12|^2, v12 = v02 - v01
    float n01 = sqrtf(s11);
    float n02 = sqrtf(s22);
    float n12 = sqrtf(s33);
    float* po = out_hyper + (size_t)h * 3;
    po[0] = s12 / (n01 * n02);
    po[1] = (s11 - s12) / (n01 * n12);
    po[2] = (s22 - s12) / (n12 * n02);
}

// ---------------- fallback: fused f32 straight from x ----------------
__global__ __launch_bounds__(256) void fused_f32_kernel(
    const float* __restrict__ x,
    const int* __restrict__ ei,
    const int* __restrict__ hi,
    float* __restrict__ out_edge,
    float* __restrict__ out_hyper,
    int E, int H, int nEB, int T) {

    long long b = blockIdx.x;
    long long aBefore = (b * (long long)nEB) / T;
    long long aAfter  = ((b + 1) * (long long)nEB) / T;
    int t   = threadIdx.x;
    int grp = t >> 4;
    int sub = t & 15;
    int c0  = sub * 4;
    int c1  = c0 + 64;

    if (aAfter > aBefore) {
        long long e = aBefore * 16 + grp;
        if (e >= E) return;
        int s = ei[e];
        int d = ei[(size_t)E + e];
        const float* xs = x + (size_t)s * DIM;
        const float* xd = x + (size_t)d * DIM;
        v4f s0 = *reinterpret_cast<const v4f*>(xs + c0);
        v4f s1 = *reinterpret_cast<const v4f*>(xs + c1);
        v4f d0 = *reinterpret_cast<const v4f*>(xd + c0);
        v4f d1 = *reinterpret_cast<const v4f*>(xd + c1);
        v4f r0 = s0 - d0;
        v4f r1 = s1 - d1;
        float* po = out_edge + (size_t)e * DIM;
        __builtin_nontemporal_store(r0, reinterpret_cast<v4f*>(po + c0));
        __builtin_nontemporal_store(r1, reinterpret_cast<v4f*>(po + c1));
    } else {
        long long hb = b - aBefore;
        long long h  = hb * 16 + grp;
        if (h >= H) return;
        int ia = hi[h];
        int ib = hi[(size_t)H + h];
        int ic = hi[2 * (size_t)H + h];
        const float* pa = x + (size_t)ia * DIM;
        const float* pb = x + (size_t)ib * DIM;
        const float* pc = x + (size_t)ic * DIM;
        v4f a0 = *reinterpret_cast<const v4f*>(pa + c0);
        v4f a1 = *reinterpret_cast<const v4f*>(pa + c1);
        v4f b0 = *reinterpret_cast<const v4f*>(pb + c0);
        v4f b1 = *reinterpret_cast<const v4f*>(pb + c1);
        v4f q0 = *reinterpret_cast<const v4f*>(pc + c0);
        v4f q1 = *reinterpret_cast<const v4f*>(pc + c1);
        float s11 = 0.f, s22 = 0.f, s12 = 0.f;
#define ACC(A, B, C) { float v01 = (A) - (B); float v02 = (A) - (C); \
        s11 = fmaf(v01, v01, s11); s22 = fmaf(v02, v02, s22); s12 = fmaf(v01, v02, s12); }
        ACC(a0.x, b0.x, q0.x) ACC(a0.y, b0.y, q0.y) ACC(a0.z, b0.z, q0.z) ACC(a0.w, b0.w, q0.w)
        ACC(a1.x, b1.x, q1.x) ACC(a1.y, b1.y, q1.y) ACC(a1.z, b1.z, q1.z) ACC(a1.w, b1.w, q1.w)
#undef ACC
#pragma unroll
        for (int m = 1; m < 16; m <<= 1) {
            s11 += __shfl_xor(s11, m);
            s22 += __shfl_xor(s22, m);
            s12 += __shfl_xor(s12, m);
        }
        if (sub == 0) {
            float s33 = s11 + s22 - 2.f * s12;
            float n01 = sqrtf(s11);
            float n02 = sqrtf(s22);
            float n12 = sqrtf(s33);
            float* po = out_hyper + (size_t)h * 3;
            po[0] = s12 / (n01 * n02);
            po[1] = (s11 - s12) / (n01 * n12);
            po[2] = (s22 - s12) / (n12 * n02);
        }
    }
}

extern "C" void kernel_launch(void* const* d_in, const int* in_sizes, int n_in,
                              void* d_out, int out_size, void* d_ws, size_t ws_size,
                              hipStream_t stream) {
    const float* x  = (const float*)d_in[0];
    const int*   ei = (const int*)d_in[1];   // (2, E)
    const int*   hi = (const int*)d_in[2];   // (3, H)

    const long long ND = (long long)in_sizes[0];   // N * D
    const long long N  = ND / DIM;
    const int E = in_sizes[1] / 2;
    const int H = in_sizes[2] / 3;

    float* out_edge  = (float*)d_out;                  // (E, D)
    float* out_hyper = out_edge + (size_t)E * DIM;     // (H, 3)

    const size_t need = (size_t)ND * sizeof(_Float16)        // sliced fp16 x
                      + (size_t)12 * H * sizeof(float) + 64; // partial planes
    if (ws_size >= need) {
        _Float16* xsl = (_Float16*)d_ws;
        // 16-byte align the partials
        size_t off = ((size_t)ND * sizeof(_Float16) + 15) & ~(size_t)15;
        float* P = (float*)((char*)d_ws + off);

        {
            long long total8 = ND / 8;
            long long grid = (total8 + 255) / 256;
            cvt_sliced_kernel<<<(dim3)(unsigned)grid, 256, 0, stream>>>(x, xsl, N, total8);
        }
        {
            int CE = (E + 63) / 64;                // edge chunks (64 edges each)
            int CH = (H + 63) / 64;                // hyper chunks
            int C  = CE + CH;
            long long grid = (long long)C * 4;     // x4 slices
            fusedA_kernel<<<(dim3)(unsigned)grid, 256, 0, stream>>>(
                xsl, ei, hi, out_edge, P, E, H, N, CE, C);
        }
        {
            long long grid = ((long long)H + 255) / 256;
            hyperB_kernel<<<(dim3)(unsigned)grid, 256, 0, stream>>>(P, out_hyper, H);
        }
    } else {
        int nEB = (E + 15) / 16;
        int nHB = (H + 15) / 16;
        int T   = nEB + nHB;
        fused_f32_kernel<<<T, 256, 0, stream>>>(x, ei, hi, out_edge, out_hyper, E, H, nEB, T);
    }
}